// Round 1
// baseline (789.250 us; speedup 1.0000x reference)
//
#include <hip/hip_runtime.h>
#include <math.h>

// ---------------------------------------------------------------------------
// EncoderBlock (QANet-style) fp32 implementation for MI355X.
// B=16, C=128, L=1024, H=8, DK=16, K=7, NCONV=4.
//
// Pipeline (each kernel fully fuses one block stage):
//   k_prep : transpose 10 weight mats -> wT[c][o]; mask -> maskf
//   k_pe   : out = x + pos_encoding
//   k_conv : LN -> depthwise K=7 -> pointwise GEMM -> ReLU -> +res   (x4)
//   k_qkv  : LN -> 3 GEMMs -> q,k,v in [B,H,L,DK]
//   k_attn : scores+softmax(no-max-trick)+PV, K/V streamed via scalar loads
//   k_oproj: GEMM + bias + residual
//   k_ffn  : LN -> GEMM+ReLU -> GEMM + bias + residual -> d_out
//
// GEMM scheme: wave owns 16 output channels; weights arrive as wave-uniform
// s_load_dwordx16 rows (SGPR operands to v_fmac); activations via one
// ds_read_b32 per K-step. Epilogue stores coalesced (lane = L position).
// ---------------------------------------------------------------------------

#define CC 128
#define LL 1024
#define TL 64          // L-tile for GEMM kernels
#define NEGF (-1e30f)

// ---------------- ws layout (floats) ----------------
// act0, act1, qw, kw, vw, ab : 2,097,152 each
// wT: 10*16384   maskf: 16384
#define ACT_N   2097152
#define OFF_ACT0 0
#define OFF_ACT1 (ACT_N)
#define OFF_QW   (2*ACT_N)
#define OFF_KW   (3*ACT_N)
#define OFF_VW   (4*ACT_N)
#define OFF_AB   (5*ACT_N)
#define OFF_WT   (6*ACT_N)
#define OFF_MF   (6*ACT_N + 10*16384)

// ---------------------------------------------------------------------------
// k_prep: blocks 0..39 transpose (10 mats x 4 row-groups of 32), 40..47 maskf
// ---------------------------------------------------------------------------
__global__ __launch_bounds__(256) void k_prep(
    const float* __restrict__ pw, const float* __restrict__ wq,
    const float* __restrict__ wk, const float* __restrict__ wv_,
    const float* __restrict__ wo, const float* __restrict__ w1,
    const float* __restrict__ w2, const unsigned char* __restrict__ mask,
    float* __restrict__ wT, float* __restrict__ maskf)
{
    __shared__ float td[32][33];
    int blk = blockIdx.x;
    int t = threadIdx.x;
    if (blk < 40) {
        int mat = blk >> 2, og = blk & 3;
        const float* src;
        if (mat < 4)      src = pw + mat * 16384;
        else if (mat == 4) src = wq;
        else if (mat == 5) src = wk;
        else if (mat == 6) src = wv_;
        else if (mat == 7) src = wo;
        else if (mat == 8) src = w1;
        else               src = w2;
        float* dst = wT + mat * 16384;
        // process 128 cols in 4 chunks of 32 to keep LDS tiny
        for (int cg = 0; cg < 4; ++cg) {
            for (int i = t; i < 1024; i += 256) {
                int o = i >> 5, c = i & 31;
                td[o][c] = src[(og * 32 + o) * 128 + cg * 32 + c];
            }
            __syncthreads();
            for (int i = t; i < 1024; i += 256) {
                int c = i >> 5, oo = i & 31;
                dst[(cg * 32 + c) * 128 + og * 32 + oo] = td[oo][c];
            }
            __syncthreads();
        }
    } else {
        int base = (blk - 40) * 2048;
        for (int i = t; i < 2048; i += 256)
            maskf[base + i] = mask[base + i] ? NEGF : 3.0e38f;
    }
}

// ---------------------------------------------------------------------------
// k_pe: out = x + sin(l*freq(c) + phase(c))
// ---------------------------------------------------------------------------
__global__ __launch_bounds__(256) void k_pe(const float* __restrict__ x,
                                            float* __restrict__ out)
{
    int idx = blockIdx.x * 256 + threadIdx.x;   // < 2097152
    int l = idx & 1023;
    int c = (idx >> 10) & 127;
    float e = (float)(c & ~1);
    // 10000^(-e/128) = 2^(-e*log2(10000)/128)
    float base = exp2f(e * (-13.287712379549449f / 128.0f));
    float freq = (c & 1) ? -base : base;
    float ph   = (c & 1) ? 1.5707963267948966f : 0.0f;
    out[idx] = x[idx] + sinf((float)l * freq + ph);
}

// ---------------------------------------------------------------------------
// k_conv: one conv block. grid 256 (b,tile), 512 threads (8 waves).
// ---------------------------------------------------------------------------
__global__ __launch_bounds__(512) void k_conv(
    const float* __restrict__ in, float* __restrict__ out,
    const float* __restrict__ wT,                 // [128 c][128 o]
    const float* __restrict__ dw,                 // [128][7]
    const float* __restrict__ pb,                 // [128]
    const float* __restrict__ g, const float* __restrict__ nbv)
{
    __shared__ float xs[128 * 70];   // LN'd input tile with halo of 3
    __shared__ float ys[128 * 64];   // depthwise output
    const int b  = blockIdx.x >> 4;
    const int l0 = (blockIdx.x & 15) << 6;
    const int t  = threadIdx.x;
    const int lane = t & 63;
    const int wv = __builtin_amdgcn_readfirstlane(t >> 6);   // 0..7
    const float* xb = in + b * 131072;

    // ---- load tile + halo (zeros outside [0,L)) ----
    for (int i = t; i < 128 * 70; i += 512) {
        int c = i / 70;
        int col = i - c * 70;
        int gl = l0 - 3 + col;
        xs[i] = ((unsigned)gl < 1024u) ? xb[c * 1024 + gl] : 0.0f;
    }
    __syncthreads();

    // ---- LayerNorm per column (valid columns only; OOR stay zero) ----
    if (t < 70) {
        int gl = l0 - 3 + t;
        if ((unsigned)gl < 1024u) {
            float s = 0.f, ss = 0.f;
            for (int c = 0; c < 128; ++c) {
                float v = xs[c * 70 + t];
                s += v; ss = fmaf(v, v, ss);
            }
            float mu = s * 0.0078125f;
            float var = ss * 0.0078125f - mu * mu;
            float rs = rsqrtf(var + 1e-5f);
            for (int c = 0; c < 128; ++c) {
                xs[c * 70 + t] = (xs[c * 70 + t] - mu) * rs * g[c] + nbv[c];
            }
        }
    }
    __syncthreads();

    // ---- depthwise conv K=7 : wave wv handles channels wv*16..+15 ----
    for (int cc = 0; cc < 16; ++cc) {
        int c = (wv << 4) + cc;
        const float* dr = dw + c * 7;           // wave-uniform
        const float* xr = xs + c * 70 + lane;
        float a =          dr[0] * xr[0];
        a = fmaf(dr[1], xr[1], a);
        a = fmaf(dr[2], xr[2], a);
        a = fmaf(dr[3], xr[3], a);
        a = fmaf(dr[4], xr[4], a);
        a = fmaf(dr[5], xr[5], a);
        a = fmaf(dr[6], xr[6], a);
        ys[c * 64 + lane] = a;
    }
    __syncthreads();

    // ---- pointwise GEMM: wave owns o = wv*16 + j ----
    const int ow = wv << 4;
    const float* wTb = wT + ow;
    float acc[16];
    #pragma unroll
    for (int j = 0; j < 16; ++j) acc[j] = 0.f;
    #pragma unroll 4
    for (int c = 0; c < 128; ++c) {
        float y = ys[c * 64 + lane];
        #pragma unroll
        for (int j = 0; j < 16; ++j)
            acc[j] = fmaf(wTb[c * 128 + j], y, acc[j]);
    }

    // ---- bias + ReLU + residual, coalesced stores ----
    float* ob = out + b * 131072;
    #pragma unroll
    for (int j = 0; j < 16; ++j) {
        int o = ow + j;
        float v = fmaxf(acc[j] + pb[o], 0.f) + xb[o * 1024 + l0 + lane];
        ob[o * 1024 + l0 + lane] = v;
    }
}

// ---------------------------------------------------------------------------
// k_qkv: LN + 3 GEMMs; outputs [B,H,L,DK] (wave wv == head wv)
// ---------------------------------------------------------------------------
__global__ __launch_bounds__(512) void k_qkv(
    const float* __restrict__ in, const float* __restrict__ wT, // wq|wk|wv T
    const float* __restrict__ bq, const float* __restrict__ bk,
    const float* __restrict__ bv,
    const float* __restrict__ g, const float* __restrict__ nbv,
    float* __restrict__ qw, float* __restrict__ kw, float* __restrict__ vw)
{
    __shared__ float ln[128 * 64];
    __shared__ float st[8 * 16 * 66];       // per-wave transpose bounce
    const int b  = blockIdx.x >> 4;
    const int l0 = (blockIdx.x & 15) << 6;
    const int t  = threadIdx.x;
    const int lane = t & 63;
    const int wv = __builtin_amdgcn_readfirstlane(t >> 6);
    const float* xb = in + b * 131072;

    for (int i = t; i < 8192; i += 512) {
        int c = i >> 6, col = i & 63;
        ln[i] = xb[c * 1024 + l0 + col];
    }
    __syncthreads();
    if (t < 64) {
        float s = 0.f, ss = 0.f;
        for (int c = 0; c < 128; ++c) {
            float v = ln[c * 64 + t];
            s += v; ss = fmaf(v, v, ss);
        }
        float mu = s * 0.0078125f;
        float var = ss * 0.0078125f - mu * mu;
        float rs = rsqrtf(var + 1e-5f);
        for (int c = 0; c < 128; ++c)
            ln[c * 64 + t] = (ln[c * 64 + t] - mu) * rs * g[c] + nbv[c];
    }
    __syncthreads();

    const int ow = wv << 4;
    const int dq = lane & 3, l2 = lane >> 2;
    for (int pass = 0; pass < 3; ++pass) {
        const float* wTb = wT + pass * 16384 + ow;
        const float* bias = (pass == 0) ? bq : (pass == 1) ? bk : bv;
        float* outp = (pass == 0) ? qw : (pass == 1) ? kw : vw;
        float acc[16];
        #pragma unroll
        for (int j = 0; j < 16; ++j) acc[j] = 0.f;
        #pragma unroll 4
        for (int c = 0; c < 128; ++c) {
            float y = ln[c * 64 + lane];
            #pragma unroll
            for (int j = 0; j < 16; ++j)
                acc[j] = fmaf(wTb[c * 128 + j], y, acc[j]);
        }
        // bounce through LDS to store [l][16] rows coalesced
        float* stw = st + wv * 1056;
        #pragma unroll
        for (int j = 0; j < 16; ++j)
            stw[j * 66 + lane] = acc[j] + bias[ow + j];
        // same-wave RAW on LDS: in-order per wave (compiler inserts waits)
        float* op = outp + ((size_t)(b * 8 + wv) * 1024 + l0) * 16;
        #pragma unroll
        for (int r = 0; r < 4; ++r) {
            int llx = l2 + (r << 4);
            float4 pk;
            pk.x = stw[(dq * 4 + 0) * 66 + llx];
            pk.y = stw[(dq * 4 + 1) * 66 + llx];
            pk.z = stw[(dq * 4 + 2) * 66 + llx];
            pk.w = stw[(dq * 4 + 3) * 66 + llx];
            *(float4*)(op + llx * 16 + dq * 4) = pk;
        }
    }
}

// ---------------------------------------------------------------------------
// k_attn: grid 512 = (b,h) x 4 query-chunks of 256. 1 query/thread.
// K/V/maskf rows are wave-uniform -> scalar loads (SGPR), 2-deep pipeline.
// Softmax without max-subtraction (scores bounded; masked -> exp(-1e30)=0).
// ---------------------------------------------------------------------------
__global__ __launch_bounds__(256) void k_attn(
    const float* __restrict__ q, const float* __restrict__ k,
    const float* __restrict__ v, const float* __restrict__ mfv,
    float* __restrict__ ab)
{
    const int bh = blockIdx.x >> 2;
    const int b  = bh >> 3;
    const int h  = bh & 7;
    const int l  = (blockIdx.x & 3) * 256 + threadIdx.x;

    const float* qr = q + ((size_t)bh * 1024 + l) * 16;
    const float* kr = k + (size_t)bh * 16384;
    const float* vr = v + (size_t)bh * 16384;
    const float* mf = mfv + b * 1024;

    float qv[16];
    #pragma unroll
    for (int d = 0; d < 16; ++d) qv[d] = qr[d] * 0.25f;   // fold 1/sqrt(DK)

    float acc[16];
    #pragma unroll
    for (int d = 0; d < 16; ++d) acc[d] = 0.f;
    float sum = 0.f;

    float ka[16], va[16], ma;
    float kb2[16], vb2[16], mb2;

#define LOADKV(K, V, M, idx) { \
        const float* _kp = kr + (idx) * 16; const float* _vp = vr + (idx) * 16; \
        _Pragma("unroll") for (int d = 0; d < 16; ++d) { K[d] = _kp[d]; V[d] = _vp[d]; } \
        M = mf[idx]; }
#define STEPKV(K, V, M) { \
        float s = qv[0] * K[0]; \
        _Pragma("unroll") for (int d = 1; d < 16; ++d) s = fmaf(qv[d], K[d], s); \
        s = fminf(s, M); \
        float p = __expf(s); \
        sum += p; \
        _Pragma("unroll") for (int d = 0; d < 16; ++d) acc[d] = fmaf(p, V[d], acc[d]); }

    LOADKV(ka, va, ma, 0)
    for (int m = 0; m < 1024; m += 2) {
        LOADKV(kb2, vb2, mb2, m + 1)
        STEPKV(ka, va, ma)
        int m2 = (m + 2 <= 1023) ? (m + 2) : 1023;
        LOADKV(ka, va, ma, m2)
        STEPKV(kb2, vb2, mb2)
    }
#undef LOADKV
#undef STEPKV

    float inv = 1.0f / (sum + 1e-37f);
    float* op = ab + ((size_t)b * 128 + h * 16) * 1024 + l;
    #pragma unroll
    for (int d = 0; d < 16; ++d) op[d * 1024] = acc[d] * inv;
}

// ---------------------------------------------------------------------------
// k_oproj: GEMM(wo) + bias + residual
// ---------------------------------------------------------------------------
__global__ __launch_bounds__(512) void k_oproj(
    const float* __restrict__ in, const float* __restrict__ wT,
    const float* __restrict__ bo, const float* __restrict__ res,
    float* __restrict__ out)
{
    __shared__ float as[128 * 64];
    const int b  = blockIdx.x >> 4;
    const int l0 = (blockIdx.x & 15) << 6;
    const int t  = threadIdx.x;
    const int lane = t & 63;
    const int wv = __builtin_amdgcn_readfirstlane(t >> 6);
    const float* xb = in + b * 131072;

    for (int i = t; i < 8192; i += 512) {
        int c = i >> 6, col = i & 63;
        as[i] = xb[c * 1024 + l0 + col];
    }
    __syncthreads();

    const int ow = wv << 4;
    const float* wTb = wT + ow;
    float acc[16];
    #pragma unroll
    for (int j = 0; j < 16; ++j) acc[j] = 0.f;
    #pragma unroll 4
    for (int c = 0; c < 128; ++c) {
        float y = as[c * 64 + lane];
        #pragma unroll
        for (int j = 0; j < 16; ++j)
            acc[j] = fmaf(wTb[c * 128 + j], y, acc[j]);
    }
    const float* rb = res + b * 131072;
    float* ob = out + b * 131072;
    #pragma unroll
    for (int j = 0; j < 16; ++j) {
        int o = ow + j;
        ob[o * 1024 + l0 + lane] = acc[j] + bo[o] + rb[o * 1024 + l0 + lane];
    }
}

// ---------------------------------------------------------------------------
// k_ffn: LN -> GEMM(w1)+ReLU -> GEMM(w2) + bias + residual -> d_out
// ---------------------------------------------------------------------------
__global__ __launch_bounds__(512) void k_ffn(
    const float* __restrict__ in,
    const float* __restrict__ w1T, const float* __restrict__ w2T,
    const float* __restrict__ b1, const float* __restrict__ b2,
    const float* __restrict__ g, const float* __restrict__ nbv,
    float* __restrict__ out)
{
    __shared__ float ln[128 * 64];    // LN result, then reused for hidden h
    const int b  = blockIdx.x >> 4;
    const int l0 = (blockIdx.x & 15) << 6;
    const int t  = threadIdx.x;
    const int lane = t & 63;
    const int wv = __builtin_amdgcn_readfirstlane(t >> 6);
    const float* xb = in + b * 131072;

    for (int i = t; i < 8192; i += 512) {
        int c = i >> 6, col = i & 63;
        ln[i] = xb[c * 1024 + l0 + col];
    }
    __syncthreads();
    if (t < 64) {
        float s = 0.f, ss = 0.f;
        for (int c = 0; c < 128; ++c) {
            float v = ln[c * 64 + t];
            s += v; ss = fmaf(v, v, ss);
        }
        float mu = s * 0.0078125f;
        float var = ss * 0.0078125f - mu * mu;
        float rs = rsqrtf(var + 1e-5f);
        for (int c = 0; c < 128; ++c)
            ln[c * 64 + t] = (ln[c * 64 + t] - mu) * rs * g[c] + nbv[c];
    }
    __syncthreads();

    const int ow = wv << 4;
    // GEMM1
    float acc[16];
    #pragma unroll
    for (int j = 0; j < 16; ++j) acc[j] = 0.f;
    {
        const float* wTb = w1T + ow;
        #pragma unroll 4
        for (int c = 0; c < 128; ++c) {
            float y = ln[c * 64 + lane];
            #pragma unroll
            for (int j = 0; j < 16; ++j)
                acc[j] = fmaf(wTb[c * 128 + j], y, acc[j]);
        }
    }
    __syncthreads();          // everyone done reading ln
    #pragma unroll
    for (int j = 0; j < 16; ++j)
        ln[(ow + j) * 64 + lane] = fmaxf(acc[j] + b1[ow + j], 0.f);
    __syncthreads();
    // GEMM2
    #pragma unroll
    for (int j = 0; j < 16; ++j) acc[j] = 0.f;
    {
        const float* wTb = w2T + ow;
        #pragma unroll 4
        for (int c = 0; c < 128; ++c) {
            float y = ln[c * 64 + lane];
            #pragma unroll
            for (int j = 0; j < 16; ++j)
                acc[j] = fmaf(wTb[c * 128 + j], y, acc[j]);
        }
    }
    float* ob = out + b * 131072;
    #pragma unroll
    for (int j = 0; j < 16; ++j) {
        int o = ow + j;
        ob[o * 1024 + l0 + lane] = acc[j] + b2[o] + xb[o * 1024 + l0 + lane];
    }
}

// ---------------------------------------------------------------------------
extern "C" void kernel_launch(void* const* d_in, const int* in_sizes, int n_in,
                              void* d_out, int out_size, void* d_ws, size_t ws_size,
                              hipStream_t stream)
{
    const float* x    = (const float*)d_in[0];
    const unsigned char* mask = (const unsigned char*)d_in[1];
    const float* dw_w = (const float*)d_in[2];
    const float* pw_w = (const float*)d_in[3];
    const float* pw_b = (const float*)d_in[4];
    const float* ng   = (const float*)d_in[5];
    const float* nb   = (const float*)d_in[6];
    const float* wq   = (const float*)d_in[7];
    const float* bq   = (const float*)d_in[8];
    const float* wk   = (const float*)d_in[9];
    const float* bk   = (const float*)d_in[10];
    const float* wv   = (const float*)d_in[11];
    const float* bv   = (const float*)d_in[12];
    const float* wo   = (const float*)d_in[13];
    const float* bo   = (const float*)d_in[14];
    const float* w1   = (const float*)d_in[15];
    const float* b1   = (const float*)d_in[16];
    const float* w2   = (const float*)d_in[17];
    const float* b2   = (const float*)d_in[18];

    float* ws   = (float*)d_ws;
    float* act0 = ws + OFF_ACT0;
    float* act1 = ws + OFF_ACT1;
    float* qw   = ws + OFF_QW;
    float* kw   = ws + OFF_KW;
    float* vw   = ws + OFF_VW;
    float* ab   = ws + OFF_AB;
    float* wT   = ws + OFF_WT;
    float* mf   = ws + OFF_MF;

    k_prep<<<48, 256, 0, stream>>>(pw_w, wq, wk, wv, wo, w1, w2, mask, wT, mf);
    k_pe<<<8192, 256, 0, stream>>>(x, act0);

    // conv blocks ping-pong: act0 -> act1 -> act0 -> act1 -> act0
    k_conv<<<256, 512, 0, stream>>>(act0, act1, wT + 0 * 16384, dw_w + 0,
                                    pw_b + 0,   ng + 0,   nb + 0);
    k_conv<<<256, 512, 0, stream>>>(act1, act0, wT + 1 * 16384, dw_w + 896,
                                    pw_b + 128, ng + 128, nb + 128);
    k_conv<<<256, 512, 0, stream>>>(act0, act1, wT + 2 * 16384, dw_w + 1792,
                                    pw_b + 256, ng + 256, nb + 256);
    k_conv<<<256, 512, 0, stream>>>(act1, act0, wT + 3 * 16384, dw_w + 2688,
                                    pw_b + 384, ng + 384, nb + 384);

    k_qkv<<<256, 512, 0, stream>>>(act0, wT + 4 * 16384, bq, bk, bv,
                                   ng + 4 * 128, nb + 4 * 128, qw, kw, vw);
    k_attn<<<512, 256, 0, stream>>>(qw, kw, vw, mf, ab);
    k_oproj<<<256, 512, 0, stream>>>(ab, wT + 7 * 16384, bo, act0, act1);
    k_ffn<<<256, 512, 0, stream>>>(act1, wT + 8 * 16384, wT + 9 * 16384,
                                   b1, b2, ng + 5 * 128, nb + 5 * 128,
                                   (float*)d_out);
}